// Round 1
// baseline (1504.710 us; speedup 1.0000x reference)
//
#include <hip/hip_runtime.h>

// GCN decoder: 2x GCNConv (with self-loops, symmetric norm) + FC to 1024.
// n = 50000 nodes, E = 800000 directed edges, feats 64 -> 64 -> 32 -> 1024.

#define TB 256

__global__ void k_init_deg(float* __restrict__ deg, int n) {
    int i = blockIdx.x * TB + threadIdx.x;
    if (i < n) deg[i] = 1.0f;  // self-loop contributes 1 to every node's degree
}

__global__ void k_deg_accum(const int* __restrict__ dst, float* __restrict__ deg, int E) {
    int e = blockIdx.x * TB + threadIdx.x;
    if (e < E) atomicAdd(&deg[dst[e]], 1.0f);
}

__global__ void k_rsqrt_inplace(float* __restrict__ deg, int n) {
    int i = blockIdx.x * TB + threadIdx.x;
    if (i < n) deg[i] = rsqrtf(deg[i]);  // deg >= 1 always
}

// Y[n,64] = X[n,64] @ W[64,64]; W staged in LDS; 4 rows per 256-thread block.
__global__ void k_gemm_x64(const float* __restrict__ X, const float* __restrict__ W,
                           float* __restrict__ Y, int n) {
    __shared__ float Ws[64 * 64];
    for (int i = threadIdx.x; i < 64 * 64; i += TB) Ws[i] = W[i];
    __syncthreads();
    int c = threadIdx.x & 63;
    int r = blockIdx.x * 4 + (threadIdx.x >> 6);
    if (r >= n) return;
    const float* x = X + (size_t)r * 64;
    float acc = 0.f;
#pragma unroll
    for (int k = 0; k < 64; ++k) acc = fmaf(x[k], Ws[k * 64 + c], acc);
    Y[(size_t)r * 64 + c] = acc;
}

// Y[n,32] = X[n,64] @ W[64,32]; 8 rows per block.
__global__ void k_gemm_64_32(const float* __restrict__ X, const float* __restrict__ W,
                             float* __restrict__ Y, int n) {
    __shared__ float Ws[64 * 32];
    for (int i = threadIdx.x; i < 64 * 32; i += TB) Ws[i] = W[i];
    __syncthreads();
    int c = threadIdx.x & 31;
    int r = blockIdx.x * 8 + (threadIdx.x >> 5);
    if (r >= n) return;
    const float* x = X + (size_t)r * 64;
    float acc = 0.f;
#pragma unroll
    for (int k = 0; k < 64; ++k) acc = fmaf(x[k], Ws[k * 32 + c], acc);
    Y[(size_t)r * 32 + c] = acc;
}

// Edge scatter, 64 feats: 16 threads per edge, each handles 4 consecutive feats.
__global__ void k_scatter64(const int* __restrict__ src, const int* __restrict__ dst,
                            const float* __restrict__ dinv, const float* __restrict__ H,
                            float* __restrict__ agg, int E) {
    long long i = (long long)blockIdx.x * TB + threadIdx.x;
    int e = (int)(i >> 4);
    if (e >= E) return;
    int t = ((int)i & 15) * 4;
    int s = src[e], d = dst[e];
    float w = dinv[s] * dinv[d];
    float4 v = *(const float4*)(H + (size_t)s * 64 + t);
    float* p = agg + (size_t)d * 64 + t;
    atomicAdd(p + 0, v.x * w);
    atomicAdd(p + 1, v.y * w);
    atomicAdd(p + 2, v.z * w);
    atomicAdd(p + 3, v.w * w);
}

// Edge scatter, 32 feats: 8 threads per edge.
__global__ void k_scatter32(const int* __restrict__ src, const int* __restrict__ dst,
                            const float* __restrict__ dinv, const float* __restrict__ H,
                            float* __restrict__ agg, int E) {
    long long i = (long long)blockIdx.x * TB + threadIdx.x;
    int e = (int)(i >> 3);
    if (e >= E) return;
    int t = ((int)i & 7) * 4;
    int s = src[e], d = dst[e];
    float w = dinv[s] * dinv[d];
    float4 v = *(const float4*)(H + (size_t)s * 32 + t);
    float* p = agg + (size_t)d * 32 + t;
    atomicAdd(p + 0, v.x * w);
    atomicAdd(p + 1, v.y * w);
    atomicAdd(p + 2, v.z * w);
    atomicAdd(p + 3, v.w * w);
}

// agg[i] = relu(agg[i] + H[i]*dinv[r]^2 + b[c])   (self-loop folded in), width 64
__global__ void k_fin1(const float* __restrict__ H, const float* __restrict__ dinv,
                       const float* __restrict__ b, float* __restrict__ agg, int n) {
    size_t i = (size_t)blockIdx.x * TB + threadIdx.x;
    if (i >= (size_t)n * 64) return;
    int r = (int)(i >> 6), c = (int)(i & 63);
    float dv = dinv[r];
    float v = agg[i] + H[i] * dv * dv + b[c];
    agg[i] = fmaxf(v, 0.0f);
}

// same, width 32, no relu
__global__ void k_fin2(const float* __restrict__ H, const float* __restrict__ dinv,
                       const float* __restrict__ b, float* __restrict__ agg, int n) {
    size_t i = (size_t)blockIdx.x * TB + threadIdx.x;
    if (i >= (size_t)n * 32) return;
    int r = (int)(i >> 5), c = (int)(i & 31);
    float dv = dinv[r];
    agg[i] = agg[i] + H[i] * dv * dv + b[c];
}

// Y[n,1024] = X[n,32] @ W[32,1024] + bias; one thread per output element.
__global__ void k_fc(const float* __restrict__ X, const float* __restrict__ W,
                     const float* __restrict__ bias, float* __restrict__ Y, int n) {
    size_t i = (size_t)blockIdx.x * TB + threadIdx.x;
    if (i >= (size_t)n * 1024) return;
    int r = (int)(i >> 10), c = (int)(i & 1023);
    const float* x = X + (size_t)r * 32;
    float acc = bias[c];
#pragma unroll
    for (int k = 0; k < 32; ++k) acc = fmaf(x[k], W[k * 1024 + c], acc);
    Y[i] = acc;
}

extern "C" void kernel_launch(void* const* d_in, const int* in_sizes, int n_in,
                              void* d_out, int out_size, void* d_ws, size_t ws_size,
                              hipStream_t stream) {
    const float* z   = (const float*)d_in[0];
    const int*   ei  = (const int*)d_in[1];
    const float* W1  = (const float*)d_in[2];
    const float* b1  = (const float*)d_in[3];
    const float* W2  = (const float*)d_in[4];
    const float* b2  = (const float*)d_in[5];
    const float* Wfc = (const float*)d_in[6];
    const float* bfc = (const float*)d_in[7];
    float* out = (float*)d_out;

    int n = in_sizes[0] / 64;
    int E = in_sizes[1] / 2;
    const int* src = ei;
    const int* dst = ei + E;

    // Workspace layout (floats):
    //   dinv[nPad] | bufA[n*64] (h1 -> h2 | agg2) | bufB[n*64] (agg1 -> hA)
    int nPad = (n + 63) & ~63;
    float* dinv = (float*)d_ws;
    float* bufA = dinv + nPad;
    float* bufB = bufA + (size_t)n * 64;
    float* h2   = bufA;
    float* agg2 = bufA + (size_t)n * 32;

    // ---- degree / norm ----
    k_init_deg<<<(n + TB - 1) / TB, TB, 0, stream>>>(dinv, n);
    k_deg_accum<<<(E + TB - 1) / TB, TB, 0, stream>>>(dst, dinv, E);
    k_rsqrt_inplace<<<(n + TB - 1) / TB, TB, 0, stream>>>(dinv, n);

    // ---- conv1: h1 = z @ W1 ; aggregate ; +b1, relu ----
    hipMemsetAsync(bufB, 0, (size_t)n * 64 * sizeof(float), stream);
    k_gemm_x64<<<(n + 3) / 4, TB, 0, stream>>>(z, W1, bufA, n);
    {
        long long tot = (long long)E * 16;
        k_scatter64<<<(int)((tot + TB - 1) / TB), TB, 0, stream>>>(src, dst, dinv, bufA, bufB, E);
    }
    k_fin1<<<(int)(((size_t)n * 64 + TB - 1) / TB), TB, 0, stream>>>(bufA, dinv, b1, bufB, n);

    // ---- conv2: h2 = hA @ W2 ; aggregate ; +b2 ----
    k_gemm_64_32<<<(n + 7) / 8, TB, 0, stream>>>(bufB, W2, h2, n);
    hipMemsetAsync(agg2, 0, (size_t)n * 32 * sizeof(float), stream);
    {
        long long tot = (long long)E * 8;
        k_scatter32<<<(int)((tot + TB - 1) / TB), TB, 0, stream>>>(src, dst, dinv, h2, agg2, E);
    }
    k_fin2<<<(int)(((size_t)n * 32 + TB - 1) / TB), TB, 0, stream>>>(h2, dinv, b2, agg2, n);

    // ---- fc: out = h2f @ Wfc + bfc ----
    {
        size_t tot = (size_t)n * 1024;
        k_fc<<<(int)((tot + TB - 1) / TB), TB, 0, stream>>>(agg2, Wfc, bfc, out, n);
    }
}

// Round 2
// 688.617 us; speedup vs baseline: 2.1851x; 2.1851x over previous
//
#include <hip/hip_runtime.h>

// GCN decoder: 2x GCNConv (self-loops, symmetric norm) + FC to 1024.
// n = 50000 nodes, E = 800000 directed edges, feats 64 -> 64 -> 32 -> 1024.
// Round 2: CSR-by-dst built per call; gather-based aggregation (no float atomics).

#define TB 256

// ---- CSR build ----------------------------------------------------------

__global__ void k_hist(const int* __restrict__ dst, int* __restrict__ cnt, int E) {
    int e = blockIdx.x * TB + threadIdx.x;
    if (e < E) atomicAdd(&cnt[dst[e]], 1);
}

__global__ void k_dinv(const int* __restrict__ cnt, float* __restrict__ dinv, int n) {
    int i = blockIdx.x * TB + threadIdx.x;
    if (i < n) dinv[i] = rsqrtf((float)(cnt[i] + 1));  // +1 self-loop
}

// Exclusive scan of cnt[0..n) -> off[0..n], single block of 1024 threads.
__global__ void k_scan(const int* __restrict__ cnt, int* __restrict__ off, int n) {
    __shared__ int wsum[16];
    __shared__ int carry_s;
    int lane = threadIdx.x & 63;
    int wid = threadIdx.x >> 6;
    if (threadIdx.x == 0) carry_s = 0;
    __syncthreads();
    for (int base = 0; base < n; base += 1024) {
        int i = base + threadIdx.x;
        int v = (i < n) ? cnt[i] : 0;
        int x = v;  // inclusive wave scan
#pragma unroll
        for (int ofs = 1; ofs < 64; ofs <<= 1) {
            int t = __shfl_up(x, ofs, 64);
            if (lane >= ofs) x += t;
        }
        if (lane == 63) wsum[wid] = x;
        __syncthreads();
        int wprefix = 0;
        for (int wv = 0; wv < wid; ++wv) wprefix += wsum[wv];
        int carry = carry_s;
        if (i < n) off[i] = carry + wprefix + x - v;
        __syncthreads();
        if (threadIdx.x == 0) {
            int tot = 0;
            for (int wv = 0; wv < 16; ++wv) tot += wsum[wv];
            carry_s += tot;
        }
        __syncthreads();
    }
    if (threadIdx.x == 0) off[n] = carry_s;
}

__global__ void k_fill(const int* __restrict__ src, const int* __restrict__ dst,
                       const int* __restrict__ off, int* __restrict__ cursor,
                       int* __restrict__ eSrc, int E) {
    int e = blockIdx.x * TB + threadIdx.x;
    if (e >= E) return;
    int d = dst[e];
    int pos = off[d] + atomicAdd(&cursor[d], 1);
    eSrc[pos] = src[e];
}

// ---- dense GEMMs --------------------------------------------------------

// Y[n,64] = X[n,64] @ W[64,64]; W staged in LDS; 4 rows per 256-thread block.
__global__ void k_gemm_x64(const float* __restrict__ X, const float* __restrict__ W,
                           float* __restrict__ Y, int n) {
    __shared__ float Ws[64 * 64];
    for (int i = threadIdx.x; i < 64 * 64; i += TB) Ws[i] = W[i];
    __syncthreads();
    int c = threadIdx.x & 63;
    int r = blockIdx.x * 4 + (threadIdx.x >> 6);
    if (r >= n) return;
    const float* x = X + (size_t)r * 64;
    float acc = 0.f;
#pragma unroll
    for (int k = 0; k < 64; ++k) acc = fmaf(x[k], Ws[k * 64 + c], acc);
    Y[(size_t)r * 64 + c] = acc;
}

// Y[n,32] = X[n,64] @ W[64,32]; 8 rows per block.
__global__ void k_gemm_64_32(const float* __restrict__ X, const float* __restrict__ W,
                             float* __restrict__ Y, int n) {
    __shared__ float Ws[64 * 32];
    for (int i = threadIdx.x; i < 64 * 32; i += TB) Ws[i] = W[i];
    __syncthreads();
    int c = threadIdx.x & 31;
    int r = blockIdx.x * 8 + (threadIdx.x >> 5);
    if (r >= n) return;
    const float* x = X + (size_t)r * 64;
    float acc = 0.f;
#pragma unroll
    for (int k = 0; k < 64; ++k) acc = fmaf(x[k], Ws[k * 32 + c], acc);
    Y[(size_t)r * 32 + c] = acc;
}

// ---- gather-based aggregation (fused norm + self-loop + bias [+relu]) ----

// out[i,c] = relu( (sum_{s in N(i)} dinv[s]*H[s,c] + H[i,c]*dinv[i]) * dinv[i] + b[c] )
// One wave per node, lane = feature (64 feats).
__global__ void k_agg64(const float* __restrict__ H, const int* __restrict__ off,
                        const int* __restrict__ eSrc, const float* __restrict__ dinv,
                        const float* __restrict__ b, float* __restrict__ out, int n) {
    int node = blockIdx.x * 4 + (threadIdx.x >> 6);
    if (node >= n) return;
    int lane = threadIdx.x & 63;
    int j0 = off[node], j1 = off[node + 1];
    float acc = 0.f;
    for (int j = j0; j < j1; ++j) {
        int s = eSrc[j];
        acc = fmaf(dinv[s], H[(size_t)s * 64 + lane], acc);
    }
    float dv = dinv[node];
    float v = fmaf(acc + H[(size_t)node * 64 + lane] * dv, dv, b[lane]);
    out[(size_t)node * 64 + lane] = fmaxf(v, 0.f);
}

// Same, 32 feats, no relu. Half-wave per node.
__global__ void k_agg32(const float* __restrict__ H, const int* __restrict__ off,
                        const int* __restrict__ eSrc, const float* __restrict__ dinv,
                        const float* __restrict__ b, float* __restrict__ out, int n) {
    int node = blockIdx.x * 8 + (threadIdx.x >> 5);
    if (node >= n) return;
    int lane = threadIdx.x & 31;
    int j0 = off[node], j1 = off[node + 1];
    float acc = 0.f;
    for (int j = j0; j < j1; ++j) {
        int s = eSrc[j];
        acc = fmaf(dinv[s], H[(size_t)s * 32 + lane], acc);
    }
    float dv = dinv[node];
    out[(size_t)node * 32 + lane] = fmaf(acc + H[(size_t)node * 32 + lane] * dv, dv, b[lane]);
}

// ---- FC -----------------------------------------------------------------

// Y[n,1024] = X[n,32] @ W[32,1024] + bias; one thread per output element.
__global__ void k_fc(const float* __restrict__ X, const float* __restrict__ W,
                     const float* __restrict__ bias, float* __restrict__ Y, int n) {
    size_t i = (size_t)blockIdx.x * TB + threadIdx.x;
    if (i >= (size_t)n * 1024) return;
    int r = (int)(i >> 10), c = (int)(i & 1023);
    const float* x = X + (size_t)r * 32;
    float acc = bias[c];
#pragma unroll
    for (int k = 0; k < 32; ++k) acc = fmaf(x[k], W[k * 1024 + c], acc);
    Y[i] = acc;
}

// ---- launch -------------------------------------------------------------

extern "C" void kernel_launch(void* const* d_in, const int* in_sizes, int n_in,
                              void* d_out, int out_size, void* d_ws, size_t ws_size,
                              hipStream_t stream) {
    const float* z   = (const float*)d_in[0];
    const int*   ei  = (const int*)d_in[1];
    const float* W1  = (const float*)d_in[2];
    const float* b1  = (const float*)d_in[3];
    const float* W2  = (const float*)d_in[4];
    const float* b2  = (const float*)d_in[5];
    const float* Wfc = (const float*)d_in[6];
    const float* bfc = (const float*)d_in[7];
    float* out = (float*)d_out;

    int n = in_sizes[0] / 64;
    int E = in_sizes[1] / 2;
    const int* src = ei;
    const int* dst = ei + E;

    // Workspace layout (4-byte words):
    //   cnt[n] | cursor[n] | off[n+1] | eSrc[E] | dinv[n] | bufA[n*64] | bufB[n*64]
    // conv2 overlays bufA: h2 = bufA[0..n*32), agg2 = bufA[n*32..n*64)
    int* cnt    = (int*)d_ws;
    int* cursor = cnt + n;
    int* off    = cursor + n;
    int* eSrc   = off + (n + 1);
    float* dinv = (float*)(eSrc + E);
    float* bufA = dinv + n;
    float* bufB = bufA + (size_t)n * 64;
    float* h2   = bufA;
    float* agg2 = bufA + (size_t)n * 32;

    // ---- CSR build + norms ----
    hipMemsetAsync(cnt, 0, (size_t)2 * n * sizeof(int), stream);  // cnt + cursor
    k_hist<<<(E + TB - 1) / TB, TB, 0, stream>>>(dst, cnt, E);
    k_dinv<<<(n + TB - 1) / TB, TB, 0, stream>>>(cnt, dinv, n);
    k_scan<<<1, 1024, 0, stream>>>(cnt, off, n);
    k_fill<<<(E + TB - 1) / TB, TB, 0, stream>>>(src, dst, off, cursor, eSrc, E);

    // ---- conv1: h1 = z @ W1 ; gather-agg (+b1, relu) -> bufB ----
    k_gemm_x64<<<(n + 3) / 4, TB, 0, stream>>>(z, W1, bufA, n);
    k_agg64<<<(n + 3) / 4, TB, 0, stream>>>(bufA, off, eSrc, dinv, b1, bufB, n);

    // ---- conv2: h2 = bufB @ W2 ; gather-agg (+b2) -> agg2 ----
    k_gemm_64_32<<<(n + 7) / 8, TB, 0, stream>>>(bufB, W2, h2, n);
    k_agg32<<<(n + 7) / 8, TB, 0, stream>>>(h2, off, eSrc, dinv, b2, agg2, n);

    // ---- fc: out = agg2 @ Wfc + bfc ----
    {
        size_t tot = (size_t)n * 1024;
        k_fc<<<(int)((tot + TB - 1) / TB), TB, 0, stream>>>(agg2, Wfc, bfc, out, n);
    }
}